// Round 14
// baseline (539.226 us; speedup 1.0000x reference)
//
#include <hip/hip_runtime.h>
#include <math.h>

// Problem constants
#define B_    64
#define S_    4096
#define HID   64
#define LIFT  256
#define MODES 16
#define NL    4

// Workspace layout (float-sized slots). Total 17,101,824 <= proven 17,108,992.
#define OFF_H     0                       // packed h (uint): B*HID*S = 16,777,216
#define OFF_ETB   16777216                // packed twiddles Etab[s][32]: 131,072
#define OFF_XFY   (OFF_ETB + 131072)      // xf fp32 [b][i][32] OR packed yk [b][o][32]
#define OFF_SKH   (OFF_XFY + 131072)      // ushort skip hi [l][o][c]: 8192 floats
#define OFF_SKL   (OFF_SKH + 8192)
#define OFF_W2HI  (OFF_SKL + 8192)        // ushort lift w2 hi [o][c2]
#define OFF_W2LO  (OFF_W2HI + 8192)
#define OFF_P1HI  (OFF_W2LO + 8192)       // ushort proj w1 hi [c2][c]
#define OFF_P1LO  (OFF_P1HI + 8192)
#define OFF_PART  (OFF_P1LO + 8192)       // 12,288 (single-writer stores)
#define OFF_W1B   (OFF_PART + 12288)      // WXY float2[256] + WB float[256]

typedef short short8 __attribute__((ext_vector_type(8)));
typedef float f32x4  __attribute__((ext_vector_type(4)));
typedef unsigned uint8v __attribute__((ext_vector_type(8)));
#define MFMA16 __builtin_amdgcn_mfma_f32_16x16x32_bf16

// gelu via A&S 7.1.28: erf(z) ~= 1 - P6(z)^-16. SCALAR form — R8's packed/
// reassociated variants flipped a bf16 rounding boundary (absmax 3.6e-6 >
// 8.4e-10 threshold). The check demands fp32-bit-stable arithmetic: only
// layout/schedule changes are safe; no reassociation of this chain.
__device__ __forceinline__ float gelu_f(float x) {
  float z = fabsf(x) * 0.70710678118654752440f;
  float p = 1.0f + z * (0.0705230784f + z * (0.0422820123f +
            z * (0.0092705272f + z * (0.0001520143f +
            z * (0.0002765672f + z * 0.0000430638f)))));
  float r = __builtin_amdgcn_rcpf(p);   // approx v_rcp_f32 (1 ulp)
  r = r * r;                            // p^-2
  r = r * r;                            // p^-4
  r = r * r;                            // p^-8
  r = r * r;                            // p^-16
  float q = 0.5f * r;                   // 0.5*(1-erf(|z|)) tail
  float phi = (x >= 0.0f) ? (1.0f - q) : q;  // normal CDF of x (at z-scale)
  return x * phi;
}
__device__ __forceinline__ unsigned short f2bf(float x) {   // RNE (init only)
  unsigned u = __float_as_uint(x);
  u += 0x7fffu + ((u >> 16) & 1u);
  return (unsigned short)(u >> 16);
}
__device__ __forceinline__ float bf2f(unsigned short b) {
  return __uint_as_float(((unsigned)b) << 16);
}
__device__ __forceinline__ unsigned packsplit(float x) {    // hi | lo<<16 (init only)
  unsigned short hi = f2bf(x);
  unsigned short lo = f2bf(x - bf2f(hi));
  return (unsigned)hi | ((unsigned)lo << 16);
}

// ---- hot-path conversion primitives (HW forms the compiler won't emit) ----
// v_cvt_pk_bf16_f32: lo16 = bf16(a), hi16 = bf16(b), RNE. No builtin on
// gfx950 (learn_hip m240) -> inline asm.
__device__ __forceinline__ unsigned cvtpk2(float a, float b) {
  unsigned d;
  asm("v_cvt_pk_bf16_f32 %0, %1, %2" : "=v"(d) : "v"(a), "v"(b));
  return d;
}
// hi/lo split of a PAIR directly into packed fragment dwords.
__device__ __forceinline__ void split2pk(float a, float b,
                                         unsigned& hpk, unsigned& lpk) {
  hpk = cvtpk2(a, b);
  float ha = __uint_as_float(hpk << 16);
  float hb = __uint_as_float(hpk & 0xffff0000u);
  lpk = cvtpk2(a - ha, b - hb);
}
// packsplit for a pair: ua = hi_a | lo_a<<16, ub = hi_b | lo_b<<16.
__device__ __forceinline__ void packsplit2(float a, float b,
                                           unsigned& ua, unsigned& ub) {
  unsigned hpk, lpk;
  split2pk(a, b, hpk, lpk);
  ua = __builtin_amdgcn_perm(lpk, hpk, 0x05040100u);  // [h.b0,h.b1,l.b0,l.b1]
  ub = __builtin_amdgcn_perm(lpk, hpk, 0x07060302u);  // [h.b2,h.b3,l.b2,l.b3]
}
// unpack 8 packed (hi|lo<<16) dwords -> hi short8 + lo short8 via v_perm.
__device__ __forceinline__ void unpk8(const unsigned* pk, short8& h8, short8& l8) {
  unsigned* hp = (unsigned*)&h8;
  unsigned* lp = (unsigned*)&l8;
  #pragma unroll
  for (int p = 0; p < 4; ++p) {
    hp[p] = __builtin_amdgcn_perm(pk[2*p+1], pk[2*p], 0x05040100u);
    lp[p] = __builtin_amdgcn_perm(pk[2*p+1], pk[2*p], 0x07060302u);
  }
}
__device__ __forceinline__ void unpk8v(const uint8v v, short8& h8, short8& l8) {
  unsigned* hp = (unsigned*)&h8;
  unsigned* lp = (unsigned*)&l8;
  #pragma unroll
  for (int p = 0; p < 4; ++p) {
    hp[p] = __builtin_amdgcn_perm(v[2*p+1], v[2*p], 0x05040100u);
    lp[p] = __builtin_amdgcn_perm(v[2*p+1], v[2*p], 0x07060302u);
  }
}

// ---------------------------------------------------------------- init ----
// grid 256. Twiddles via sincosf (bf16-split pack error dominates).
// R14: W1B de-padded — WXY float2[256] (x,y) at +0, WB float[256] (bias)
// at +512. The old float4 carried a zero .w = 8 wasted VGPRs in k_lift's
// per-kstep working set (the -12-reg lever to reach 4 waves/SIMD).
__global__ void k_init(const float* __restrict__ lift_w2,
                       const float* __restrict__ skip_w,
                       const float* __restrict__ proj_w1,
                       const float* __restrict__ lift_w1,
                       const float* __restrict__ lift_b1,
                       float* __restrict__ ws) {
  unsigned* etab = (unsigned*)(ws + OFF_ETB);
  unsigned short* skh = (unsigned short*)(ws + OFF_SKH);
  unsigned short* skl = (unsigned short*)(ws + OFF_SKL);
  unsigned short* w2hi = (unsigned short*)(ws + OFF_W2HI);
  unsigned short* w2lo = (unsigned short*)(ws + OFF_W2LO);
  unsigned short* p1hi = (unsigned short*)(ws + OFF_P1HI);
  unsigned short* p1lo = (unsigned short*)(ws + OFF_P1LO);
  float2* wxy = (float2*)(ws + OFF_W1B);
  float*  wb  = ws + OFF_W1B + 512;
  int idx = blockIdx.x * 256 + threadIdx.x;
  int stride = gridDim.x * 256;
  // Etab[s][c]: c<16 -> cos(th*m*s), c>=16 -> -sin(th*m*s), m = c&15 (s-major)
  for (int k = idx; k < 4096 * 32; k += stride) {
    int s = k >> 5, c = k & 31;
    int m = c & 15;
    int r = (m * s) & 4095;
    float th = (float)(2.0 * 3.14159265358979323846 / 4096.0) * (float)r;
    float sn, cn; sincosf(th, &sn, &cn);
    float v = (c < 16) ? cn : -sn;
    etab[k] = packsplit(v);
  }
  for (int k = idx; k < NL * HID * HID; k += stride) {  // natural [l][o][c]
    float w = skip_w[k];
    unsigned short hi = f2bf(w);
    skh[k] = hi; skl[k] = f2bf(w - bf2f(hi));
  }
  for (int k = idx; k < HID * LIFT; k += stride) {      // natural [o][c2]
    float w = lift_w2[k];
    unsigned short hi = f2bf(w);
    w2hi[k] = hi; w2lo[k] = f2bf(w - bf2f(hi));
  }
  for (int k = idx; k < LIFT * HID; k += stride) {      // natural [c2][c]
    float w = proj_w1[k];
    unsigned short hi = f2bf(w);
    p1hi[k] = hi; p1lo[k] = f2bf(w - bf2f(hi));
  }
  for (int k = idx; k < LIFT; k += stride) {            // de-padded stage-1
    wxy[k] = make_float2(lift_w1[2 * k], lift_w1[2 * k + 1]);
    wb[k]  = lift_b1[k];
  }
  for (int k = idx; k < 12288; k += stride)             // zero part
    ws[OFF_PART + k] = 0.f;
}

// ---------------------------------------------------------------- lift ----
// grid (S/128, B), block 128 (2 waves). R14: (128,4) — W1B de-pad drops 8
// VGPRs from the kstep working set (wxy 16 + wb 8 = 24 vs padded 32);
// the bound pressures the allocator to land <=128 unified (64 arch + 64
// acc) -> 4 waves/SIMD (was 140 -> 3, occupancy pinned 23%). Dot written
// character-identically (wx*x + wy*y + b) -> same codegen, bit-identical.
__global__ __launch_bounds__(128, 4) void k_lift(
    const float* __restrict__ x, const float* __restrict__ W1B,
    const float* __restrict__ b2,
    const unsigned short* __restrict__ Whi,
    const unsigned short* __restrict__ Wlo,
    unsigned* __restrict__ Hp) {
  const float2* WXY = (const float2*)W1B;
  const float*  WB  = W1B + 512;
  int tid = threadIdx.x;
  int b = blockIdx.y, s0 = blockIdx.x * 128;
  int lane = tid & 63, wv = tid >> 6, quad = lane >> 4, n16 = lane & 15;
  int sw = s0 + wv * 64;
  int cq = quad * 8;    // lane's j-base inside each 32-row K-chunk
  float2 xv[4];
  #pragma unroll
  for (int nt = 0; nt < 4; ++nt)
    xv[nt] = ((const float2*)x)[b * S_ + sw + nt * 16 + n16];
  f32x4 acc[4][4];
  #pragma unroll
  for (int mt = 0; mt < 4; ++mt)
    #pragma unroll
    for (int nt = 0; nt < 4; ++nt) acc[mt][nt] = (f32x4){0.f, 0.f, 0.f, 0.f};

  #pragma unroll 1
  for (int k = 0; k < 8; ++k) {
    short8 ah[4], al[4];
    #pragma unroll
    for (int mt = 0; mt < 4; ++mt) {
      int aoff = (mt * 16 + n16) * 256 + k * 32 + cq;
      ah[mt] = *(const short8*)(Whi + aoff);
      al[mt] = *(const short8*)(Wlo + aoff);
    }
    float2 wxy[8];
    float  wbv[8];
    #pragma unroll
    for (int j = 0; j < 8; ++j) wxy[j] = WXY[k * 32 + cq + j];
    *(float4*)&wbv[0] = *(const float4*)&WB[k * 32 + cq];
    *(float4*)&wbv[4] = *(const float4*)&WB[k * 32 + cq + 4];
    #pragma unroll
    for (int nt = 0; nt < 4; ++nt) {
      float t[8];
      #pragma unroll
      for (int j = 0; j < 8; ++j)
        t[j] = gelu_f(wxy[j].x * xv[nt].x + wxy[j].y * xv[nt].y + wbv[j]);
      short8 bh, bl;
      unsigned* bhw = (unsigned*)&bh;
      unsigned* blw = (unsigned*)&bl;
      #pragma unroll
      for (int p = 0; p < 4; ++p)
        split2pk(t[2*p], t[2*p+1], bhw[p], blw[p]);
      #pragma unroll
      for (int mt = 0; mt < 4; ++mt) {
        acc[mt][nt] = MFMA16(ah[mt], bh, acc[mt][nt], 0, 0, 0);
        acc[mt][nt] = MFMA16(ah[mt], bl, acc[mt][nt], 0, 0, 0);
        acc[mt][nt] = MFMA16(al[mt], bh, acc[mt][nt], 0, 0, 0);
      }
    }
  }
  #pragma unroll
  for (int mt = 0; mt < 4; ++mt) {
    int o0 = mt * 16 + quad * 4;
    float4 bb = *(const float4*)&b2[o0];
    #pragma unroll
    for (int nt = 0; nt < 4; ++nt) {
      int sc = sw + nt * 16 + n16;
      unsigned* hp = Hp + ((size_t)b * HID + o0) * S_ + sc;
      unsigned u0, u1, u2, u3;
      packsplit2(acc[mt][nt][0] + bb.x, acc[mt][nt][1] + bb.y, u0, u1);
      packsplit2(acc[mt][nt][2] + bb.z, acc[mt][nt][3] + bb.w, u2, u3);
      hp[0]            = u0;
      hp[(size_t)S_]   = u1;
      hp[(size_t)2*S_] = u2;
      hp[(size_t)3*S_] = u3;
    }
  }
}

// --------------------------------------------------------- forward DFT ----
// grid (4 msplit, B, 4 ksplit), block 256 (4 waves) -> 1024 blocks, 4/CU.
// Wave g = ks*4+wv covers K-range [g*256, +256). Block partial is LDS-
// reduced then atomicAdd'ed into xf (16 commutative fp32 contributors).
// xf zeroed per layer by hipMemsetAsync before this kernel.
__global__ __launch_bounds__(256, 4) void k_fft_fwd(
    const unsigned* __restrict__ Hp, const unsigned* __restrict__ Etab,
    float* __restrict__ xf) {
  __shared__ float red[4 * 512];
  int tid = threadIdx.x;
  int i0 = blockIdx.x * 16, b = blockIdx.y, ks = blockIdx.z;
  int lane = tid & 63, wv = tid >> 6, quad = lane >> 4, n16 = lane & 15;
  const unsigned* hb = Hp + ((size_t)b * HID + i0 + n16) * S_;
  int g = ks * 4 + wv;               // K-chunk 0..15
  f32x4 acc0 = (f32x4){0.f,0.f,0.f,0.f}, acc1 = (f32x4){0.f,0.f,0.f,0.f};
  #pragma unroll 1
  for (int kt = 0; kt < 8; ++kt) {
    int sb = g * 256 + kt * 32 + quad * 8;
    uint8v av = *(const uint8v*)(hb + sb);
    short8 ah, al;
    unpk8v(av, ah, al);
    unsigned q0[8], q1[8];
    #pragma unroll
    for (int j = 0; j < 8; ++j) {
      q0[j] = Etab[(sb + j) * 32 + n16];
      q1[j] = Etab[(sb + j) * 32 + 16 + n16];
    }
    short8 bh0, bl0, bh1, bl1;
    unpk8(q0, bh0, bl0);
    unpk8(q1, bh1, bl1);
    acc0 = MFMA16(ah, bh0, acc0, 0, 0, 0);
    acc0 = MFMA16(ah, bl0, acc0, 0, 0, 0);
    acc0 = MFMA16(al, bh0, acc0, 0, 0, 0);
    acc1 = MFMA16(ah, bh1, acc1, 0, 0, 0);
    acc1 = MFMA16(ah, bl1, acc1, 0, 0, 0);
    acc1 = MFMA16(al, bh1, acc1, 0, 0, 0);
  }
  // D: row = quad*4+r (i_local), col = n16 (+16 for acc1)
  #pragma unroll
  for (int r = 0; r < 4; ++r) {
    red[wv * 512 + (quad * 4 + r) * 32 + n16]      = acc0[r];
    red[wv * 512 + (quad * 4 + r) * 32 + 16 + n16] = acc1[r];
  }
  __syncthreads();
  #pragma unroll
  for (int u = 0; u < 2; ++u) {
    int t = u * 256 + tid;
    int il = t >> 5, c = t & 31;
    float v = red[t] + red[512 + t] + red[1024 + t] + red[1536 + t];
    atomicAdd(&xf[(size_t)b * 2048 + (i0 + il) * 32 + c], v);
  }
}

// ----------------------------------------------------------- mode mix ----
// grid (B), block 256, single block per b (in-place safe: ALL of xf[b] is
// staged to LDS before any yk write). Thread owns (o = tid>>2, m = mq..mq+3)
// -> weight reads are 2 float4 vloads per i2; LDS reads broadcast. Per-
// output i2 chain unchanged -> bit-identical. (R12 proven: -12us)
__global__ __launch_bounds__(256) void k_mix(
    const float* __restrict__ wr_, const float* __restrict__ wi_,
    float* __restrict__ xfy) {
  int tid = threadIdx.x;
  int b = blockIdx.x;
  __shared__ float xr[HID * MODES], xi[HID * MODES];
  const float* xfb = xfy + (size_t)b * 2048;
  for (int u = tid; u < HID * MODES; u += 256) {
    int i = u >> 4, m = u & 15;
    xr[u] = xfb[i * 32 + m];
    xi[u] = xfb[i * 32 + 16 + m];
  }
  __syncthreads();
  const float invS = 1.0f / (float)S_;
  unsigned* yk = (unsigned*)xfy + (size_t)b * 2048;
  int o = tid >> 2, mq = (tid & 3) * 4;
  float yr[4] = {0.f, 0.f, 0.f, 0.f};
  float yj[4] = {0.f, 0.f, 0.f, 0.f};
  for (int i2 = 0; i2 < HID; ++i2) {
    float4 w4 = *(const float4*)&wr_[((size_t)i2 * HID + o) * MODES + mq];
    float4 v4 = *(const float4*)&wi_[((size_t)i2 * HID + o) * MODES + mq];
    float4 x4 = *(const float4*)&xr[i2 * MODES + mq];
    float4 y4 = *(const float4*)&xi[i2 * MODES + mq];
    yr[0] += x4.x * w4.x - y4.x * v4.x;  yj[0] += x4.x * v4.x + y4.x * w4.x;
    yr[1] += x4.y * w4.y - y4.y * v4.y;  yj[1] += x4.y * v4.y + y4.y * w4.y;
    yr[2] += x4.z * w4.z - y4.z * v4.z;  yj[2] += x4.z * v4.z + y4.z * w4.z;
    yr[3] += x4.w * w4.w - y4.w * v4.w;  yj[3] += x4.w * v4.w + y4.w * w4.w;
  }
  #pragma unroll
  for (int mm = 0; mm < 4; ++mm) {
    int m = mq + mm;
    float fac = (m == 0) ? invS : 2.f * invS;
    unsigned ur, ui;
    packsplit2(yr[mm] * fac, yj[mm] * fac, ur, ui);
    yk[o * 32 + m]      = ur;
    yk[o * 32 + 16 + m] = ui;
  }
}

// --------------------------------------------- irfft + skip + (gelu) ----
// grid (S/128, B), block 128 (2 waves), (128,3) — R13-proven. Per-wave
// work identical; v_perm unpacks + packsplit2 epilogue; scalar bias+gelu
// (bit-stable). In-place safe: wave-private columns.
template <bool ACT>
__global__ __launch_bounds__(128, 3) void k_spec_skip(
    const unsigned short* __restrict__ Shi,
    const unsigned short* __restrict__ Slo,
    const float* __restrict__ skb,
    const unsigned* __restrict__ Yk,
    const unsigned* __restrict__ Etab,
    unsigned* __restrict__ Hp) {
  int tid = threadIdx.x;
  int s0 = blockIdx.x * 128, b = blockIdx.y;
  int lane = tid & 63, wv = tid >> 6, quad = lane >> 4, n16 = lane & 15;
  int sw = s0 + wv * 64;
  f32x4 acc[4][4];
  #pragma unroll
  for (int mt = 0; mt < 4; ++mt)
    #pragma unroll
    for (int nt = 0; nt < 4; ++nt) acc[mt][nt] = (f32x4){0.f,0.f,0.f,0.f};
  // ---- irfft phase: yk A-frags live only in this scope ----
  {
    short8 yh[4], yl[4];
    #pragma unroll
    for (int mt = 0; mt < 4; ++mt) {
      uint8v yv = *(const uint8v*)(Yk + (size_t)b * 2048 + (mt * 16 + n16) * 32 + quad * 8);
      unpk8v(yv, yh[mt], yl[mt]);
    }
    #pragma unroll
    for (int nt = 0; nt < 4; ++nt) {
      int sc = sw + nt * 16 + n16;
      uint8v tv = *(const uint8v*)(Etab + (size_t)sc * 32 + quad * 8);
      short8 th, tl;
      unpk8v(tv, th, tl);
      #pragma unroll
      for (int mt = 0; mt < 4; ++mt) {
        acc[mt][nt] = MFMA16(yh[mt], th, acc[mt][nt], 0, 0, 0);
        acc[mt][nt] = MFMA16(yh[mt], tl, acc[mt][nt], 0, 0, 0);
        acc[mt][nt] = MFMA16(yl[mt], th, acc[mt][nt], 0, 0, 0);
      }
    }
  }
  // ---- skip GEMM: K=64 (2 ksteps); A-frags loaded per-kk ----
  const unsigned* hb = Hp + (size_t)b * HID * S_;
  #pragma unroll
  for (int kk = 0; kk < 2; ++kk) {
    short8 skh[4], skl[4];
    #pragma unroll
    for (int mt = 0; mt < 4; ++mt) {
      int off = (mt * 16 + n16) * 64 + kk * 32 + quad * 8;
      skh[mt] = *(const short8*)(Shi + off);
      skl[mt] = *(const short8*)(Slo + off);
    }
    #pragma unroll
    for (int nt = 0; nt < 4; ++nt) {
      int sc = sw + nt * 16 + n16;
      unsigned pk[8];
      #pragma unroll
      for (int j = 0; j < 8; ++j)
        pk[j] = hb[(size_t)(kk * 32 + quad * 8 + j) * S_ + sc];
      short8 bh, bl;
      unpk8(pk, bh, bl);
      #pragma unroll
      for (int mt = 0; mt < 4; ++mt) {
        acc[mt][nt] = MFMA16(skh[mt], bh, acc[mt][nt], 0, 0, 0);
        acc[mt][nt] = MFMA16(skh[mt], bl, acc[mt][nt], 0, 0, 0);
        acc[mt][nt] = MFMA16(skl[mt], bh, acc[mt][nt], 0, 0, 0);
      }
    }
  }
  // epilogue: bias + (gelu) + pack + store
  #pragma unroll
  for (int mt = 0; mt < 4; ++mt) {
    int o0 = mt * 16 + quad * 4;
    float4 bb = *(const float4*)&skb[o0];
    #pragma unroll
    for (int nt = 0; nt < 4; ++nt) {
      int sc = sw + nt * 16 + n16;
      float v0 = acc[mt][nt][0] + bb.x;
      float v1 = acc[mt][nt][1] + bb.y;
      float v2 = acc[mt][nt][2] + bb.z;
      float v3 = acc[mt][nt][3] + bb.w;
      if (ACT) { v0 = gelu_f(v0); v1 = gelu_f(v1); v2 = gelu_f(v2); v3 = gelu_f(v3); }
      unsigned u0, u1, u2, u3;
      packsplit2(v0, v1, u0, u1);
      packsplit2(v2, v3, u2, u3);
      unsigned* hp = Hp + ((size_t)b * HID + o0) * S_ + sc;
      hp[0]            = u0;
      hp[(size_t)S_]   = u1;
      hp[(size_t)2*S_] = u2;
      hp[(size_t)3*S_] = u3;
    }
  }
}

// ------------------------------------------------- projection + mean ----
// grid (S/64, B), block 512 (8 waves), (512,6) — R13 form. Tile staged
// ONCE, conflict-free frag-ready pair-dword layout; single-writer part
// stores; scalar epilogue bit-stable.
__global__ __launch_bounds__(512, 6) void k_proj(
    const unsigned short* __restrict__ Phi,
    const unsigned short* __restrict__ Plo,
    const float* __restrict__ pb1, const float* __restrict__ pw2,
    const unsigned* __restrict__ Hp, float* __restrict__ part) {
  __shared__ unsigned BpH[64 * 34];
  __shared__ unsigned BpL[64 * 34];
  __shared__ float red[24];
  int tid = threadIdx.x;
  int s0 = blockIdx.x * 64, b = blockIdx.y;
  int lane = tid & 63, wv = tid >> 6, quad = lane >> 4, n16 = lane & 15;
  {
    int cg = wv & 3, u0b = (wv >> 2) * 4;
    const unsigned* hpb = Hp + ((size_t)b * HID + cg * 16) * S_ + s0 + lane;
    #pragma unroll
    for (int uu = 0; uu < 4; ++uu) {
      int up = u0b + uu;
      unsigned u0 = hpb[(size_t)(2 * up) * S_];
      unsigned u1 = hpb[(size_t)(2 * up + 1) * S_];
      BpH[lane * 34 + cg * 8 + up] = __builtin_amdgcn_perm(u1, u0, 0x05040100u);
      BpL[lane * 34 + cg * 8 + up] = __builtin_amdgcn_perm(u1, u0, 0x07060302u);
    }
  }
  __syncthreads();
  int m0 = wv * 32;                      // wave owns c2 rows [m0, m0+32)
  f32x4 acc[2][4];
  #pragma unroll
  for (int mt = 0; mt < 2; ++mt)
    #pragma unroll
    for (int nt = 0; nt < 4; ++nt) acc[mt][nt] = (f32x4){0.f,0.f,0.f,0.f};
  #pragma unroll
  for (int kk = 0; kk < 2; ++kk) {
    int kb = kk * 16 + quad * 4;   // dword col base = 8 channels
    short8 ah[2], al[2];
    #pragma unroll
    for (int mt = 0; mt < 2; ++mt) {
      int aoff = (m0 + mt * 16 + n16) * 64 + kk * 32 + quad * 8;
      ah[mt] = *(const short8*)(Phi + aoff);
      al[mt] = *(const short8*)(Plo + aoff);
    }
    #pragma unroll
    for (int nt = 0; nt < 4; ++nt) {
      int sc = nt * 16 + n16;
      union { unsigned u[4]; short8 s; } Bh, Bl;
      *(uint2*)&Bh.u[0] = *(const uint2*)&BpH[sc * 34 + kb];
      *(uint2*)&Bh.u[2] = *(const uint2*)&BpH[sc * 34 + kb + 2];
      *(uint2*)&Bl.u[0] = *(const uint2*)&BpL[sc * 34 + kb];
      *(uint2*)&Bl.u[2] = *(const uint2*)&BpL[sc * 34 + kb + 2];
      #pragma unroll
      for (int mt = 0; mt < 2; ++mt) {
        acc[mt][nt] = MFMA16(ah[mt], Bh.s, acc[mt][nt], 0, 0, 0);
        acc[mt][nt] = MFMA16(ah[mt], Bl.s, acc[mt][nt], 0, 0, 0);
        acc[mt][nt] = MFMA16(al[mt], Bh.s, acc[mt][nt], 0, 0, 0);
      }
    }
  }
  // epilogue (scalar, bit-stable): gelu + pw2 dot + wave/block reduce
  float o0 = 0.f, o1 = 0.f, o2 = 0.f;
  #pragma unroll
  for (int mt = 0; mt < 2; ++mt) {
    int c2b = m0 + mt * 16 + quad * 4;
    float4 bb = *(const float4*)&pb1[c2b];
    float4 p0 = *(const float4*)&pw2[c2b];
    float4 p1 = *(const float4*)&pw2[256 + c2b];
    float4 p2 = *(const float4*)&pw2[512 + c2b];
    #pragma unroll
    for (int nt = 0; nt < 4; ++nt) {
      f32x4 a = acc[mt][nt];
      float t0 = gelu_f(a[0] + bb.x);
      float t1 = gelu_f(a[1] + bb.y);
      float t2 = gelu_f(a[2] + bb.z);
      float t3 = gelu_f(a[3] + bb.w);
      o0 += p0.x * t0 + p0.y * t1 + p0.z * t2 + p0.w * t3;
      o1 += p1.x * t0 + p1.y * t1 + p1.z * t2 + p1.w * t3;
      o2 += p2.x * t0 + p2.y * t1 + p2.z * t2 + p2.w * t3;
    }
  }
  #pragma unroll
  for (int off = 32; off > 0; off >>= 1) {
    o0 += __shfl_xor(o0, off, 64);
    o1 += __shfl_xor(o1, off, 64);
    o2 += __shfl_xor(o2, off, 64);
  }
  if (lane == 0) { red[wv*3+0] = o0; red[wv*3+1] = o1; red[wv*3+2] = o2; }
  __syncthreads();
  if (tid < 3) {
    float sum = 0.f;
    #pragma unroll
    for (int k = 0; k < 8; ++k) sum += red[k * 3 + tid];
    part[(b * 64 + blockIdx.x) * 3 + tid] = sum;   // single writer
  }
}

__global__ void k_final(const float* __restrict__ part,
                        const float* __restrict__ pb2,
                        float* __restrict__ out) {
  int t = threadIdx.x;
  if (t < B_ * 3) {
    int b = t / 3, j = t % 3;
    float s = 0.f;
    for (int k = 0; k < 64; ++k) s += part[(b * 64 + k) * 3 + j];
    out[t] = s * (1.0f / (float)S_) + pb2[j];
  }
}

// ------------------------------------------------------------- launch ----
extern "C" void kernel_launch(void* const* d_in, const int* in_sizes, int n_in,
                              void* d_out, int out_size, void* d_ws, size_t ws_size,
                              hipStream_t stream) {
  const float* x   = (const float*)d_in[0];
  const float* lw1 = (const float*)d_in[1];
  const float* lb1 = (const float*)d_in[2];
  const float* lw2 = (const float*)d_in[3];
  const float* lb2 = (const float*)d_in[4];
  const float* swr = (const float*)d_in[5];
  const float* swi = (const float*)d_in[6];
  const float* skw = (const float*)d_in[7];
  const float* skb = (const float*)d_in[8];
  const float* pw1 = (const float*)d_in[9];
  const float* pb1 = (const float*)d_in[10];
  const float* pw2 = (const float*)d_in[11];
  const float* pb2 = (const float*)d_in[12];
  float* ws = (float*)d_ws;
  unsigned* Hp  = (unsigned*)(ws + OFF_H);
  unsigned* ETB = (unsigned*)(ws + OFF_ETB);
  float*    XFY = ws + OFF_XFY;

  k_init<<<256, 256, 0, stream>>>(lw2, skw, pw1, lw1, lb1, ws);
  k_lift<<<dim3(S_ / 128, B_), 128, 0, stream>>>(
      x, ws + OFF_W1B, lb2,
      (const unsigned short*)(ws + OFF_W2HI),
      (const unsigned short*)(ws + OFF_W2LO), Hp);
  for (int l = 0; l < NL; ++l) {
    hipMemsetAsync(XFY, 0, (size_t)B_ * 2048 * sizeof(float), stream);
    k_fft_fwd<<<dim3(4, B_, 4), 256, 0, stream>>>(Hp, ETB, XFY);
    k_mix<<<B_, 256, 0, stream>>>(swr + l * HID * HID * MODES,
                                  swi + l * HID * HID * MODES, XFY);
    if (l < NL - 1)
      k_spec_skip<true><<<dim3(S_ / 128, B_), 128, 0, stream>>>(
          (const unsigned short*)(ws + OFF_SKH) + l * HID * HID,
          (const unsigned short*)(ws + OFF_SKL) + l * HID * HID,
          skb + l * HID, (const unsigned*)XFY, ETB, Hp);
    else
      k_spec_skip<false><<<dim3(S_ / 128, B_), 128, 0, stream>>>(
          (const unsigned short*)(ws + OFF_SKH) + l * HID * HID,
          (const unsigned short*)(ws + OFF_SKL) + l * HID * HID,
          skb + l * HID, (const unsigned*)XFY, ETB, Hp);
  }
  k_proj<<<dim3(S_ / 64, B_), 512, 0, stream>>>(
      (const unsigned short*)(ws + OFF_P1HI),
      (const unsigned short*)(ws + OFF_P1LO),
      pb1, pw2, Hp, ws + OFF_PART);
  k_final<<<1, 256, 0, stream>>>(ws + OFF_PART, pb2, (float*)d_out);
}

// Round 15
// 498.868 us; speedup vs baseline: 1.0809x; 1.0809x over previous
//
#include <hip/hip_runtime.h>
#include <math.h>

// Problem constants
#define B_    64
#define S_    4096
#define HID   64
#define LIFT  256
#define MODES 16
#define NL    4

// Workspace layout (float-sized slots). Total 17,101,824 <= proven 17,108,992.
#define OFF_H     0                       // packed h (uint): B*HID*S = 16,777,216
#define OFF_ETB   16777216                // packed twiddles Etab[s][32]: 131,072
#define OFF_XFY   (OFF_ETB + 131072)      // xf fp32 [b][i][32] OR packed yk [b][o][32]
#define OFF_SKH   (OFF_XFY + 131072)      // ushort skip hi [l][o][c]: 8192 floats
#define OFF_SKL   (OFF_SKH + 8192)
#define OFF_W2HI  (OFF_SKL + 8192)        // ushort lift w2 hi [o][c2]
#define OFF_W2LO  (OFF_W2HI + 8192)
#define OFF_P1HI  (OFF_W2LO + 8192)       // ushort proj w1 hi [c2][c]
#define OFF_P1LO  (OFF_P1HI + 8192)
#define OFF_PART  (OFF_P1LO + 8192)       // 12,288 (single-writer stores)
#define OFF_W1B   (OFF_PART + 12288)      // WXY float2[256] + WB float[256]

typedef short short8 __attribute__((ext_vector_type(8)));
typedef float f32x4  __attribute__((ext_vector_type(4)));
typedef unsigned uint8v __attribute__((ext_vector_type(8)));
#define MFMA16 __builtin_amdgcn_mfma_f32_16x16x32_bf16

// gelu via A&S 7.1.28: erf(z) ~= 1 - P6(z)^-16. SCALAR form — R8's packed/
// reassociated variants flipped a bf16 rounding boundary (absmax 3.6e-6 >
// 8.4e-10 threshold). The check demands fp32-bit-stable arithmetic: only
// layout/schedule changes are safe; no reassociation of this chain.
__device__ __forceinline__ float gelu_f(float x) {
  float z = fabsf(x) * 0.70710678118654752440f;
  float p = 1.0f + z * (0.0705230784f + z * (0.0422820123f +
            z * (0.0092705272f + z * (0.0001520143f +
            z * (0.0002765672f + z * 0.0000430638f)))));
  float r = __builtin_amdgcn_rcpf(p);   // approx v_rcp_f32 (1 ulp)
  r = r * r;                            // p^-2
  r = r * r;                            // p^-4
  r = r * r;                            // p^-8
  r = r * r;                            // p^-16
  float q = 0.5f * r;                   // 0.5*(1-erf(|z|)) tail
  float phi = (x >= 0.0f) ? (1.0f - q) : q;  // normal CDF of x (at z-scale)
  return x * phi;
}
__device__ __forceinline__ unsigned short f2bf(float x) {   // RNE (init only)
  unsigned u = __float_as_uint(x);
  u += 0x7fffu + ((u >> 16) & 1u);
  return (unsigned short)(u >> 16);
}
__device__ __forceinline__ float bf2f(unsigned short b) {
  return __uint_as_float(((unsigned)b) << 16);
}
__device__ __forceinline__ unsigned packsplit(float x) {    // hi | lo<<16 (init only)
  unsigned short hi = f2bf(x);
  unsigned short lo = f2bf(x - bf2f(hi));
  return (unsigned)hi | ((unsigned)lo << 16);
}

// ---- hot-path conversion primitives (HW forms the compiler won't emit) ----
// v_cvt_pk_bf16_f32: lo16 = bf16(a), hi16 = bf16(b), RNE. No builtin on
// gfx950 (learn_hip m240) -> inline asm.
__device__ __forceinline__ unsigned cvtpk2(float a, float b) {
  unsigned d;
  asm("v_cvt_pk_bf16_f32 %0, %1, %2" : "=v"(d) : "v"(a), "v"(b));
  return d;
}
// hi/lo split of a PAIR directly into packed fragment dwords.
__device__ __forceinline__ void split2pk(float a, float b,
                                         unsigned& hpk, unsigned& lpk) {
  hpk = cvtpk2(a, b);
  float ha = __uint_as_float(hpk << 16);
  float hb = __uint_as_float(hpk & 0xffff0000u);
  lpk = cvtpk2(a - ha, b - hb);
}
// packsplit for a pair: ua = hi_a | lo_a<<16, ub = hi_b | lo_b<<16.
__device__ __forceinline__ void packsplit2(float a, float b,
                                           unsigned& ua, unsigned& ub) {
  unsigned hpk, lpk;
  split2pk(a, b, hpk, lpk);
  ua = __builtin_amdgcn_perm(lpk, hpk, 0x05040100u);  // [h.b0,h.b1,l.b0,l.b1]
  ub = __builtin_amdgcn_perm(lpk, hpk, 0x07060302u);  // [h.b2,h.b3,l.b2,l.b3]
}
// unpack 8 packed (hi|lo<<16) dwords -> hi short8 + lo short8 via v_perm.
__device__ __forceinline__ void unpk8(const unsigned* pk, short8& h8, short8& l8) {
  unsigned* hp = (unsigned*)&h8;
  unsigned* lp = (unsigned*)&l8;
  #pragma unroll
  for (int p = 0; p < 4; ++p) {
    hp[p] = __builtin_amdgcn_perm(pk[2*p+1], pk[2*p], 0x05040100u);
    lp[p] = __builtin_amdgcn_perm(pk[2*p+1], pk[2*p], 0x07060302u);
  }
}
__device__ __forceinline__ void unpk8v(const uint8v v, short8& h8, short8& l8) {
  unsigned* hp = (unsigned*)&h8;
  unsigned* lp = (unsigned*)&l8;
  #pragma unroll
  for (int p = 0; p < 4; ++p) {
    hp[p] = __builtin_amdgcn_perm(v[2*p+1], v[2*p], 0x05040100u);
    lp[p] = __builtin_amdgcn_perm(v[2*p+1], v[2*p], 0x07060302u);
  }
}

// ---------------------------------------------------------------- init ----
// grid 256. Twiddles via sincosf (bf16-split pack error dominates).
// W1B de-padded: WXY float2[256] at +0, WB float[256] at +512.
__global__ void k_init(const float* __restrict__ lift_w2,
                       const float* __restrict__ skip_w,
                       const float* __restrict__ proj_w1,
                       const float* __restrict__ lift_w1,
                       const float* __restrict__ lift_b1,
                       float* __restrict__ ws) {
  unsigned* etab = (unsigned*)(ws + OFF_ETB);
  unsigned short* skh = (unsigned short*)(ws + OFF_SKH);
  unsigned short* skl = (unsigned short*)(ws + OFF_SKL);
  unsigned short* w2hi = (unsigned short*)(ws + OFF_W2HI);
  unsigned short* w2lo = (unsigned short*)(ws + OFF_W2LO);
  unsigned short* p1hi = (unsigned short*)(ws + OFF_P1HI);
  unsigned short* p1lo = (unsigned short*)(ws + OFF_P1LO);
  float2* wxy = (float2*)(ws + OFF_W1B);
  float*  wb  = ws + OFF_W1B + 512;
  int idx = blockIdx.x * 256 + threadIdx.x;
  int stride = gridDim.x * 256;
  // Etab[s][c]: c<16 -> cos(th*m*s), c>=16 -> -sin(th*m*s), m = c&15 (s-major)
  for (int k = idx; k < 4096 * 32; k += stride) {
    int s = k >> 5, c = k & 31;
    int m = c & 15;
    int r = (m * s) & 4095;
    float th = (float)(2.0 * 3.14159265358979323846 / 4096.0) * (float)r;
    float sn, cn; sincosf(th, &sn, &cn);
    float v = (c < 16) ? cn : -sn;
    etab[k] = packsplit(v);
  }
  for (int k = idx; k < NL * HID * HID; k += stride) {  // natural [l][o][c]
    float w = skip_w[k];
    unsigned short hi = f2bf(w);
    skh[k] = hi; skl[k] = f2bf(w - bf2f(hi));
  }
  for (int k = idx; k < HID * LIFT; k += stride) {      // natural [o][c2]
    float w = lift_w2[k];
    unsigned short hi = f2bf(w);
    w2hi[k] = hi; w2lo[k] = f2bf(w - bf2f(hi));
  }
  for (int k = idx; k < LIFT * HID; k += stride) {      // natural [c2][c]
    float w = proj_w1[k];
    unsigned short hi = f2bf(w);
    p1hi[k] = hi; p1lo[k] = f2bf(w - bf2f(hi));
  }
  for (int k = idx; k < LIFT; k += stride) {            // de-padded stage-1
    wxy[k] = make_float2(lift_w1[2 * k], lift_w1[2 * k + 1]);
    wb[k]  = lift_b1[k];
  }
  for (int k = idx; k < 12288; k += stride)             // zero part
    ws[OFF_PART + k] = 0.f;
}

// ---------------------------------------------------------------- lift ----
// grid (S/128, B), block 128 (2 waves), (128,3) — R15 REVERT: the (128,4)
// experiment spilled (VGPR forced to 64, FETCH 1.4MB->51MB, WRITE 66MB->
// 306MB scratch traffic, dur 70->105us). Falsified: k_lift's true working
// set is ~140 unified regs; 3 waves/SIMD is its ceiling. W1B de-pad kept
// (lighter working set, no spill pressure at 3 waves).
__global__ __launch_bounds__(128, 3) void k_lift(
    const float* __restrict__ x, const float* __restrict__ W1B,
    const float* __restrict__ b2,
    const unsigned short* __restrict__ Whi,
    const unsigned short* __restrict__ Wlo,
    unsigned* __restrict__ Hp) {
  const float2* WXY = (const float2*)W1B;
  const float*  WB  = W1B + 512;
  int tid = threadIdx.x;
  int b = blockIdx.y, s0 = blockIdx.x * 128;
  int lane = tid & 63, wv = tid >> 6, quad = lane >> 4, n16 = lane & 15;
  int sw = s0 + wv * 64;
  int cq = quad * 8;    // lane's j-base inside each 32-row K-chunk
  float2 xv[4];
  #pragma unroll
  for (int nt = 0; nt < 4; ++nt)
    xv[nt] = ((const float2*)x)[b * S_ + sw + nt * 16 + n16];
  f32x4 acc[4][4];
  #pragma unroll
  for (int mt = 0; mt < 4; ++mt)
    #pragma unroll
    for (int nt = 0; nt < 4; ++nt) acc[mt][nt] = (f32x4){0.f, 0.f, 0.f, 0.f};

  #pragma unroll 1
  for (int k = 0; k < 8; ++k) {
    short8 ah[4], al[4];
    #pragma unroll
    for (int mt = 0; mt < 4; ++mt) {
      int aoff = (mt * 16 + n16) * 256 + k * 32 + cq;
      ah[mt] = *(const short8*)(Whi + aoff);
      al[mt] = *(const short8*)(Wlo + aoff);
    }
    float2 wxy[8];
    float  wbv[8];
    #pragma unroll
    for (int j = 0; j < 8; ++j) wxy[j] = WXY[k * 32 + cq + j];
    *(float4*)&wbv[0] = *(const float4*)&WB[k * 32 + cq];
    *(float4*)&wbv[4] = *(const float4*)&WB[k * 32 + cq + 4];
    #pragma unroll
    for (int nt = 0; nt < 4; ++nt) {
      float t[8];
      #pragma unroll
      for (int j = 0; j < 8; ++j)
        t[j] = gelu_f(wxy[j].x * xv[nt].x + wxy[j].y * xv[nt].y + wbv[j]);
      short8 bh, bl;
      unsigned* bhw = (unsigned*)&bh;
      unsigned* blw = (unsigned*)&bl;
      #pragma unroll
      for (int p = 0; p < 4; ++p)
        split2pk(t[2*p], t[2*p+1], bhw[p], blw[p]);
      #pragma unroll
      for (int mt = 0; mt < 4; ++mt) {
        acc[mt][nt] = MFMA16(ah[mt], bh, acc[mt][nt], 0, 0, 0);
        acc[mt][nt] = MFMA16(ah[mt], bl, acc[mt][nt], 0, 0, 0);
        acc[mt][nt] = MFMA16(al[mt], bh, acc[mt][nt], 0, 0, 0);
      }
    }
  }
  #pragma unroll
  for (int mt = 0; mt < 4; ++mt) {
    int o0 = mt * 16 + quad * 4;
    float4 bb = *(const float4*)&b2[o0];
    #pragma unroll
    for (int nt = 0; nt < 4; ++nt) {
      int sc = sw + nt * 16 + n16;
      unsigned* hp = Hp + ((size_t)b * HID + o0) * S_ + sc;
      unsigned u0, u1, u2, u3;
      packsplit2(acc[mt][nt][0] + bb.x, acc[mt][nt][1] + bb.y, u0, u1);
      packsplit2(acc[mt][nt][2] + bb.z, acc[mt][nt][3] + bb.w, u2, u3);
      hp[0]            = u0;
      hp[(size_t)S_]   = u1;
      hp[(size_t)2*S_] = u2;
      hp[(size_t)3*S_] = u3;
    }
  }
}

// --------------------------------------------------------- forward DFT ----
// grid (4 msplit, B, 4 ksplit), block 256 (4 waves) -> 1024 blocks, 4/CU.
// Wave g = ks*4+wv covers K-range [g*256, +256). Block partial is LDS-
// reduced then atomicAdd'ed into xf (16 commutative fp32 contributors).
// xf zeroed per layer by hipMemsetAsync before this kernel.
__global__ __launch_bounds__(256, 4) void k_fft_fwd(
    const unsigned* __restrict__ Hp, const unsigned* __restrict__ Etab,
    float* __restrict__ xf) {
  __shared__ float red[4 * 512];
  int tid = threadIdx.x;
  int i0 = blockIdx.x * 16, b = blockIdx.y, ks = blockIdx.z;
  int lane = tid & 63, wv = tid >> 6, quad = lane >> 4, n16 = lane & 15;
  const unsigned* hb = Hp + ((size_t)b * HID + i0 + n16) * S_;
  int g = ks * 4 + wv;               // K-chunk 0..15
  f32x4 acc0 = (f32x4){0.f,0.f,0.f,0.f}, acc1 = (f32x4){0.f,0.f,0.f,0.f};
  #pragma unroll 1
  for (int kt = 0; kt < 8; ++kt) {
    int sb = g * 256 + kt * 32 + quad * 8;
    uint8v av = *(const uint8v*)(hb + sb);
    short8 ah, al;
    unpk8v(av, ah, al);
    unsigned q0[8], q1[8];
    #pragma unroll
    for (int j = 0; j < 8; ++j) {
      q0[j] = Etab[(sb + j) * 32 + n16];
      q1[j] = Etab[(sb + j) * 32 + 16 + n16];
    }
    short8 bh0, bl0, bh1, bl1;
    unpk8(q0, bh0, bl0);
    unpk8(q1, bh1, bl1);
    acc0 = MFMA16(ah, bh0, acc0, 0, 0, 0);
    acc0 = MFMA16(ah, bl0, acc0, 0, 0, 0);
    acc0 = MFMA16(al, bh0, acc0, 0, 0, 0);
    acc1 = MFMA16(ah, bh1, acc1, 0, 0, 0);
    acc1 = MFMA16(ah, bl1, acc1, 0, 0, 0);
    acc1 = MFMA16(al, bh1, acc1, 0, 0, 0);
  }
  // D: row = quad*4+r (i_local), col = n16 (+16 for acc1)
  #pragma unroll
  for (int r = 0; r < 4; ++r) {
    red[wv * 512 + (quad * 4 + r) * 32 + n16]      = acc0[r];
    red[wv * 512 + (quad * 4 + r) * 32 + 16 + n16] = acc1[r];
  }
  __syncthreads();
  #pragma unroll
  for (int u = 0; u < 2; ++u) {
    int t = u * 256 + tid;
    int il = t >> 5, c = t & 31;
    float v = red[t] + red[512 + t] + red[1024 + t] + red[1536 + t];
    atomicAdd(&xf[(size_t)b * 2048 + (i0 + il) * 32 + c], v);
  }
}

// ----------------------------------------------------------- mode mix ----
// grid (B), block 256, single block per b (in-place safe: ALL of xf[b] is
// staged to LDS before any yk write). Thread owns (o = tid>>2, m = mq..mq+3)
// -> weight reads are 2 float4 vloads per i2; LDS reads broadcast. Per-
// output i2 chain unchanged -> bit-identical. (R12 proven: -12us)
__global__ __launch_bounds__(256) void k_mix(
    const float* __restrict__ wr_, const float* __restrict__ wi_,
    float* __restrict__ xfy) {
  int tid = threadIdx.x;
  int b = blockIdx.x;
  __shared__ float xr[HID * MODES], xi[HID * MODES];
  const float* xfb = xfy + (size_t)b * 2048;
  for (int u = tid; u < HID * MODES; u += 256) {
    int i = u >> 4, m = u & 15;
    xr[u] = xfb[i * 32 + m];
    xi[u] = xfb[i * 32 + 16 + m];
  }
  __syncthreads();
  const float invS = 1.0f / (float)S_;
  unsigned* yk = (unsigned*)xfy + (size_t)b * 2048;
  int o = tid >> 2, mq = (tid & 3) * 4;
  float yr[4] = {0.f, 0.f, 0.f, 0.f};
  float yj[4] = {0.f, 0.f, 0.f, 0.f};
  for (int i2 = 0; i2 < HID; ++i2) {
    float4 w4 = *(const float4*)&wr_[((size_t)i2 * HID + o) * MODES + mq];
    float4 v4 = *(const float4*)&wi_[((size_t)i2 * HID + o) * MODES + mq];
    float4 x4 = *(const float4*)&xr[i2 * MODES + mq];
    float4 y4 = *(const float4*)&xi[i2 * MODES + mq];
    yr[0] += x4.x * w4.x - y4.x * v4.x;  yj[0] += x4.x * v4.x + y4.x * w4.x;
    yr[1] += x4.y * w4.y - y4.y * v4.y;  yj[1] += x4.y * v4.y + y4.y * w4.y;
    yr[2] += x4.z * w4.z - y4.z * v4.z;  yj[2] += x4.z * v4.z + y4.z * w4.z;
    yr[3] += x4.w * w4.w - y4.w * v4.w;  yj[3] += x4.w * v4.w + y4.w * w4.w;
  }
  #pragma unroll
  for (int mm = 0; mm < 4; ++mm) {
    int m = mq + mm;
    float fac = (m == 0) ? invS : 2.f * invS;
    unsigned ur, ui;
    packsplit2(yr[mm] * fac, yj[mm] * fac, ur, ui);
    yk[o * 32 + m]      = ur;
    yk[o * 32 + 16 + m] = ui;
  }
}

// --------------------------------------------- irfft + skip + (gelu) ----
// grid (S/128, B), block 128 (2 waves), (128,3) — R13-proven. Per-wave
// work identical; v_perm unpacks + packsplit2 epilogue; scalar bias+gelu
// (bit-stable). In-place safe: wave-private columns.
template <bool ACT>
__global__ __launch_bounds__(128, 3) void k_spec_skip(
    const unsigned short* __restrict__ Shi,
    const unsigned short* __restrict__ Slo,
    const float* __restrict__ skb,
    const unsigned* __restrict__ Yk,
    const unsigned* __restrict__ Etab,
    unsigned* __restrict__ Hp) {
  int tid = threadIdx.x;
  int s0 = blockIdx.x * 128, b = blockIdx.y;
  int lane = tid & 63, wv = tid >> 6, quad = lane >> 4, n16 = lane & 15;
  int sw = s0 + wv * 64;
  f32x4 acc[4][4];
  #pragma unroll
  for (int mt = 0; mt < 4; ++mt)
    #pragma unroll
    for (int nt = 0; nt < 4; ++nt) acc[mt][nt] = (f32x4){0.f,0.f,0.f,0.f};
  // ---- irfft phase: yk A-frags live only in this scope ----
  {
    short8 yh[4], yl[4];
    #pragma unroll
    for (int mt = 0; mt < 4; ++mt) {
      uint8v yv = *(const uint8v*)(Yk + (size_t)b * 2048 + (mt * 16 + n16) * 32 + quad * 8);
      unpk8v(yv, yh[mt], yl[mt]);
    }
    #pragma unroll
    for (int nt = 0; nt < 4; ++nt) {
      int sc = sw + nt * 16 + n16;
      uint8v tv = *(const uint8v*)(Etab + (size_t)sc * 32 + quad * 8);
      short8 th, tl;
      unpk8v(tv, th, tl);
      #pragma unroll
      for (int mt = 0; mt < 4; ++mt) {
        acc[mt][nt] = MFMA16(yh[mt], th, acc[mt][nt], 0, 0, 0);
        acc[mt][nt] = MFMA16(yh[mt], tl, acc[mt][nt], 0, 0, 0);
        acc[mt][nt] = MFMA16(yl[mt], th, acc[mt][nt], 0, 0, 0);
      }
    }
  }
  // ---- skip GEMM: K=64 (2 ksteps); A-frags loaded per-kk ----
  const unsigned* hb = Hp + (size_t)b * HID * S_;
  #pragma unroll
  for (int kk = 0; kk < 2; ++kk) {
    short8 skh[4], skl[4];
    #pragma unroll
    for (int mt = 0; mt < 4; ++mt) {
      int off = (mt * 16 + n16) * 64 + kk * 32 + quad * 8;
      skh[mt] = *(const short8*)(Shi + off);
      skl[mt] = *(const short8*)(Slo + off);
    }
    #pragma unroll
    for (int nt = 0; nt < 4; ++nt) {
      int sc = sw + nt * 16 + n16;
      unsigned pk[8];
      #pragma unroll
      for (int j = 0; j < 8; ++j)
        pk[j] = hb[(size_t)(kk * 32 + quad * 8 + j) * S_ + sc];
      short8 bh, bl;
      unpk8(pk, bh, bl);
      #pragma unroll
      for (int mt = 0; mt < 4; ++mt) {
        acc[mt][nt] = MFMA16(skh[mt], bh, acc[mt][nt], 0, 0, 0);
        acc[mt][nt] = MFMA16(skh[mt], bl, acc[mt][nt], 0, 0, 0);
        acc[mt][nt] = MFMA16(skl[mt], bh, acc[mt][nt], 0, 0, 0);
      }
    }
  }
  // epilogue: bias + (gelu) + pack + store
  #pragma unroll
  for (int mt = 0; mt < 4; ++mt) {
    int o0 = mt * 16 + quad * 4;
    float4 bb = *(const float4*)&skb[o0];
    #pragma unroll
    for (int nt = 0; nt < 4; ++nt) {
      int sc = sw + nt * 16 + n16;
      float v0 = acc[mt][nt][0] + bb.x;
      float v1 = acc[mt][nt][1] + bb.y;
      float v2 = acc[mt][nt][2] + bb.z;
      float v3 = acc[mt][nt][3] + bb.w;
      if (ACT) { v0 = gelu_f(v0); v1 = gelu_f(v1); v2 = gelu_f(v2); v3 = gelu_f(v3); }
      unsigned u0, u1, u2, u3;
      packsplit2(v0, v1, u0, u1);
      packsplit2(v2, v3, u2, u3);
      unsigned* hp = Hp + ((size_t)b * HID + o0) * S_ + sc;
      hp[0]            = u0;
      hp[(size_t)S_]   = u1;
      hp[(size_t)2*S_] = u2;
      hp[(size_t)3*S_] = u3;
    }
  }
}

// ------------------------------------------------- projection + mean ----
// grid (S/64, B), block 512 (8 waves), (512,6) — R13 form. Tile staged
// ONCE, conflict-free frag-ready pair-dword layout; single-writer part
// stores; scalar epilogue bit-stable.
__global__ __launch_bounds__(512, 6) void k_proj(
    const unsigned short* __restrict__ Phi,
    const unsigned short* __restrict__ Plo,
    const float* __restrict__ pb1, const float* __restrict__ pw2,
    const unsigned* __restrict__ Hp, float* __restrict__ part) {
  __shared__ unsigned BpH[64 * 34];
  __shared__ unsigned BpL[64 * 34];
  __shared__ float red[24];
  int tid = threadIdx.x;
  int s0 = blockIdx.x * 64, b = blockIdx.y;
  int lane = tid & 63, wv = tid >> 6, quad = lane >> 4, n16 = lane & 15;
  {
    int cg = wv & 3, u0b = (wv >> 2) * 4;
    const unsigned* hpb = Hp + ((size_t)b * HID + cg * 16) * S_ + s0 + lane;
    #pragma unroll
    for (int uu = 0; uu < 4; ++uu) {
      int up = u0b + uu;
      unsigned u0 = hpb[(size_t)(2 * up) * S_];
      unsigned u1 = hpb[(size_t)(2 * up + 1) * S_];
      BpH[lane * 34 + cg * 8 + up] = __builtin_amdgcn_perm(u1, u0, 0x05040100u);
      BpL[lane * 34 + cg * 8 + up] = __builtin_amdgcn_perm(u1, u0, 0x07060302u);
    }
  }
  __syncthreads();
  int m0 = wv * 32;                      // wave owns c2 rows [m0, m0+32)
  f32x4 acc[2][4];
  #pragma unroll
  for (int mt = 0; mt < 2; ++mt)
    #pragma unroll
    for (int nt = 0; nt < 4; ++nt) acc[mt][nt] = (f32x4){0.f,0.f,0.f,0.f};
  #pragma unroll
  for (int kk = 0; kk < 2; ++kk) {
    int kb = kk * 16 + quad * 4;   // dword col base = 8 channels
    short8 ah[2], al[2];
    #pragma unroll
    for (int mt = 0; mt < 2; ++mt) {
      int aoff = (m0 + mt * 16 + n16) * 64 + kk * 32 + quad * 8;
      ah[mt] = *(const short8*)(Phi + aoff);
      al[mt] = *(const short8*)(Plo + aoff);
    }
    #pragma unroll
    for (int nt = 0; nt < 4; ++nt) {
      int sc = nt * 16 + n16;
      union { unsigned u[4]; short8 s; } Bh, Bl;
      *(uint2*)&Bh.u[0] = *(const uint2*)&BpH[sc * 34 + kb];
      *(uint2*)&Bh.u[2] = *(const uint2*)&BpH[sc * 34 + kb + 2];
      *(uint2*)&Bl.u[0] = *(const uint2*)&BpL[sc * 34 + kb];
      *(uint2*)&Bl.u[2] = *(const uint2*)&BpL[sc * 34 + kb + 2];
      #pragma unroll
      for (int mt = 0; mt < 2; ++mt) {
        acc[mt][nt] = MFMA16(ah[mt], Bh.s, acc[mt][nt], 0, 0, 0);
        acc[mt][nt] = MFMA16(ah[mt], Bl.s, acc[mt][nt], 0, 0, 0);
        acc[mt][nt] = MFMA16(al[mt], Bh.s, acc[mt][nt], 0, 0, 0);
      }
    }
  }
  // epilogue (scalar, bit-stable): gelu + pw2 dot + wave/block reduce
  float o0 = 0.f, o1 = 0.f, o2 = 0.f;
  #pragma unroll
  for (int mt = 0; mt < 2; ++mt) {
    int c2b = m0 + mt * 16 + quad * 4;
    float4 bb = *(const float4*)&pb1[c2b];
    float4 p0 = *(const float4*)&pw2[c2b];
    float4 p1 = *(const float4*)&pw2[256 + c2b];
    float4 p2 = *(const float4*)&pw2[512 + c2b];
    #pragma unroll
    for (int nt = 0; nt < 4; ++nt) {
      f32x4 a = acc[mt][nt];
      float t0 = gelu_f(a[0] + bb.x);
      float t1 = gelu_f(a[1] + bb.y);
      float t2 = gelu_f(a[2] + bb.z);
      float t3 = gelu_f(a[3] + bb.w);
      o0 += p0.x * t0 + p0.y * t1 + p0.z * t2 + p0.w * t3;
      o1 += p1.x * t0 + p1.y * t1 + p1.z * t2 + p1.w * t3;
      o2 += p2.x * t0 + p2.y * t1 + p2.z * t2 + p2.w * t3;
    }
  }
  #pragma unroll
  for (int off = 32; off > 0; off >>= 1) {
    o0 += __shfl_xor(o0, off, 64);
    o1 += __shfl_xor(o1, off, 64);
    o2 += __shfl_xor(o2, off, 64);
  }
  if (lane == 0) { red[wv*3+0] = o0; red[wv*3+1] = o1; red[wv*3+2] = o2; }
  __syncthreads();
  if (tid < 3) {
    float sum = 0.f;
    #pragma unroll
    for (int k = 0; k < 8; ++k) sum += red[k * 3 + tid];
    part[(b * 64 + blockIdx.x) * 3 + tid] = sum;   // single writer
  }
}

__global__ void k_final(const float* __restrict__ part,
                        const float* __restrict__ pb2,
                        float* __restrict__ out) {
  int t = threadIdx.x;
  if (t < B_ * 3) {
    int b = t / 3, j = t % 3;
    float s = 0.f;
    for (int k = 0; k < 64; ++k) s += part[(b * 64 + k) * 3 + j];
    out[t] = s * (1.0f / (float)S_) + pb2[j];
  }
}

// ------------------------------------------------------------- launch ----
extern "C" void kernel_launch(void* const* d_in, const int* in_sizes, int n_in,
                              void* d_out, int out_size, void* d_ws, size_t ws_size,
                              hipStream_t stream) {
  const float* x   = (const float*)d_in[0];
  const float* lw1 = (const float*)d_in[1];
  const float* lb1 = (const float*)d_in[2];
  const float* lw2 = (const float*)d_in[3];
  const float* lb2 = (const float*)d_in[4];
  const float* swr = (const float*)d_in[5];
  const float* swi = (const float*)d_in[6];
  const float* skw = (const float*)d_in[7];
  const float* skb = (const float*)d_in[8];
  const float* pw1 = (const float*)d_in[9];
  const float* pb1 = (const float*)d_in[10];
  const float* pw2 = (const float*)d_in[11];
  const float* pb2 = (const float*)d_in[12];
  float* ws = (float*)d_ws;
  unsigned* Hp  = (unsigned*)(ws + OFF_H);
  unsigned* ETB = (unsigned*)(ws + OFF_ETB);
  float*    XFY = ws + OFF_XFY;

  k_init<<<256, 256, 0, stream>>>(lw2, skw, pw1, lw1, lb1, ws);
  k_lift<<<dim3(S_ / 128, B_), 128, 0, stream>>>(
      x, ws + OFF_W1B, lb2,
      (const unsigned short*)(ws + OFF_W2HI),
      (const unsigned short*)(ws + OFF_W2LO), Hp);
  for (int l = 0; l < NL; ++l) {
    hipMemsetAsync(XFY, 0, (size_t)B_ * 2048 * sizeof(float), stream);
    k_fft_fwd<<<dim3(4, B_, 4), 256, 0, stream>>>(Hp, ETB, XFY);
    k_mix<<<B_, 256, 0, stream>>>(swr + l * HID * HID * MODES,
                                  swi + l * HID * HID * MODES, XFY);
    if (l < NL - 1)
      k_spec_skip<true><<<dim3(S_ / 128, B_), 128, 0, stream>>>(
          (const unsigned short*)(ws + OFF_SKH) + l * HID * HID,
          (const unsigned short*)(ws + OFF_SKL) + l * HID * HID,
          skb + l * HID, (const unsigned*)XFY, ETB, Hp);
    else
      k_spec_skip<false><<<dim3(S_ / 128, B_), 128, 0, stream>>>(
          (const unsigned short*)(ws + OFF_SKH) + l * HID * HID,
          (const unsigned short*)(ws + OFF_SKL) + l * HID * HID,
          skb + l * HID, (const unsigned*)XFY, ETB, Hp);
  }
  k_proj<<<dim3(S_ / 64, B_), 512, 0, stream>>>(
      (const unsigned short*)(ws + OFF_P1HI),
      (const unsigned short*)(ws + OFF_P1LO),
      pb1, pw2, Hp, ws + OFF_PART);
  k_final<<<1, 256, 0, stream>>>(ws + OFF_PART, pb2, (float*)d_out);
}

// Round 16
// 493.490 us; speedup vs baseline: 1.0927x; 1.0109x over previous
//
#include <hip/hip_runtime.h>
#include <math.h>

// Problem constants
#define B_    64
#define S_    4096
#define HID   64
#define LIFT  256
#define MODES 16
#define NL    4

// Workspace layout (float-sized slots). Total 17,101,824 <= proven 17,108,992.
#define OFF_H     0                       // packed h (uint): B*HID*S = 16,777,216
#define OFF_ETB   16777216                // packed twiddles Etab[s][32]: 131,072
#define OFF_XFY   (OFF_ETB + 131072)      // xf fp32 [b][i][32] OR packed yk [b][o][32]
#define OFF_SKH   (OFF_XFY + 131072)      // ushort skip hi [l][o][c]: 8192 floats
#define OFF_SKL   (OFF_SKH + 8192)
#define OFF_W2HI  (OFF_SKL + 8192)        // ushort lift w2 hi [o][c2]
#define OFF_W2LO  (OFF_W2HI + 8192)
#define OFF_P1HI  (OFF_W2LO + 8192)       // ushort proj w1 hi [c2][c]
#define OFF_P1LO  (OFF_P1HI + 8192)
#define OFF_PART  (OFF_P1LO + 8192)       // 12,288 (single-writer stores)
#define OFF_W1B   (OFF_PART + 12288)      // float4[256]: (w1x, w1y, b1, 0)

typedef short short8 __attribute__((ext_vector_type(8)));
typedef float f32x4  __attribute__((ext_vector_type(4)));
typedef unsigned uint8v __attribute__((ext_vector_type(8)));
#define MFMA16 __builtin_amdgcn_mfma_f32_16x16x32_bf16

// gelu via A&S 7.1.28: erf(z) ~= 1 - P6(z)^-16. SCALAR form — R8's packed/
// reassociated variants flipped a bf16 rounding boundary (absmax 3.6e-6 >
// 8.4e-10 threshold). The check demands fp32-bit-stable arithmetic: only
// layout/schedule changes are safe; no reassociation of this chain.
__device__ __forceinline__ float gelu_f(float x) {
  float z = fabsf(x) * 0.70710678118654752440f;
  float p = 1.0f + z * (0.0705230784f + z * (0.0422820123f +
            z * (0.0092705272f + z * (0.0001520143f +
            z * (0.0002765672f + z * 0.0000430638f)))));
  float r = __builtin_amdgcn_rcpf(p);   // approx v_rcp_f32 (1 ulp)
  r = r * r;                            // p^-2
  r = r * r;                            // p^-4
  r = r * r;                            // p^-8
  r = r * r;                            // p^-16
  float q = 0.5f * r;                   // 0.5*(1-erf(|z|)) tail
  float phi = (x >= 0.0f) ? (1.0f - q) : q;  // normal CDF of x (at z-scale)
  return x * phi;
}
__device__ __forceinline__ unsigned short f2bf(float x) {   // RNE (init only)
  unsigned u = __float_as_uint(x);
  u += 0x7fffu + ((u >> 16) & 1u);
  return (unsigned short)(u >> 16);
}
__device__ __forceinline__ float bf2f(unsigned short b) {
  return __uint_as_float(((unsigned)b) << 16);
}
__device__ __forceinline__ unsigned packsplit(float x) {    // hi | lo<<16 (init only)
  unsigned short hi = f2bf(x);
  unsigned short lo = f2bf(x - bf2f(hi));
  return (unsigned)hi | ((unsigned)lo << 16);
}

// ---- hot-path conversion primitives (HW forms the compiler won't emit) ----
// v_cvt_pk_bf16_f32: lo16 = bf16(a), hi16 = bf16(b), RNE. No builtin on
// gfx950 (learn_hip m240) -> inline asm.
__device__ __forceinline__ unsigned cvtpk2(float a, float b) {
  unsigned d;
  asm("v_cvt_pk_bf16_f32 %0, %1, %2" : "=v"(d) : "v"(a), "v"(b));
  return d;
}
// hi/lo split of a PAIR directly into packed fragment dwords.
__device__ __forceinline__ void split2pk(float a, float b,
                                         unsigned& hpk, unsigned& lpk) {
  hpk = cvtpk2(a, b);
  float ha = __uint_as_float(hpk << 16);
  float hb = __uint_as_float(hpk & 0xffff0000u);
  lpk = cvtpk2(a - ha, b - hb);
}
// packsplit for a pair: ua = hi_a | lo_a<<16, ub = hi_b | lo_b<<16.
__device__ __forceinline__ void packsplit2(float a, float b,
                                           unsigned& ua, unsigned& ub) {
  unsigned hpk, lpk;
  split2pk(a, b, hpk, lpk);
  ua = __builtin_amdgcn_perm(lpk, hpk, 0x05040100u);  // [h.b0,h.b1,l.b0,l.b1]
  ub = __builtin_amdgcn_perm(lpk, hpk, 0x07060302u);  // [h.b2,h.b3,l.b2,l.b3]
}
// unpack 8 packed (hi|lo<<16) dwords -> hi short8 + lo short8 via v_perm.
__device__ __forceinline__ void unpk8(const unsigned* pk, short8& h8, short8& l8) {
  unsigned* hp = (unsigned*)&h8;
  unsigned* lp = (unsigned*)&l8;
  #pragma unroll
  for (int p = 0; p < 4; ++p) {
    hp[p] = __builtin_amdgcn_perm(pk[2*p+1], pk[2*p], 0x05040100u);
    lp[p] = __builtin_amdgcn_perm(pk[2*p+1], pk[2*p], 0x07060302u);
  }
}
__device__ __forceinline__ void unpk8v(const uint8v v, short8& h8, short8& l8) {
  unsigned* hp = (unsigned*)&h8;
  unsigned* lp = (unsigned*)&l8;
  #pragma unroll
  for (int p = 0; p < 4; ++p) {
    hp[p] = __builtin_amdgcn_perm(v[2*p+1], v[2*p], 0x05040100u);
    lp[p] = __builtin_amdgcn_perm(v[2*p+1], v[2*p], 0x07060302u);
  }
}

// ---------------------------------------------------------------- init ----
// grid 256. Twiddles via sincosf (bf16-split pack error dominates).
// R16: W1B back to R13's padded float4 (best measured: k_lift VGPR 76 /
// 496.6us vs de-padded VGPR 80 / 498.9us).
__global__ void k_init(const float* __restrict__ lift_w2,
                       const float* __restrict__ skip_w,
                       const float* __restrict__ proj_w1,
                       const float* __restrict__ lift_w1,
                       const float* __restrict__ lift_b1,
                       float* __restrict__ ws) {
  unsigned* etab = (unsigned*)(ws + OFF_ETB);
  unsigned short* skh = (unsigned short*)(ws + OFF_SKH);
  unsigned short* skl = (unsigned short*)(ws + OFF_SKL);
  unsigned short* w2hi = (unsigned short*)(ws + OFF_W2HI);
  unsigned short* w2lo = (unsigned short*)(ws + OFF_W2LO);
  unsigned short* p1hi = (unsigned short*)(ws + OFF_P1HI);
  unsigned short* p1lo = (unsigned short*)(ws + OFF_P1LO);
  float4* w1b = (float4*)(ws + OFF_W1B);
  int idx = blockIdx.x * 256 + threadIdx.x;
  int stride = gridDim.x * 256;
  // Etab[s][c]: c<16 -> cos(th*m*s), c>=16 -> -sin(th*m*s), m = c&15 (s-major)
  for (int k = idx; k < 4096 * 32; k += stride) {
    int s = k >> 5, c = k & 31;
    int m = c & 15;
    int r = (m * s) & 4095;
    float th = (float)(2.0 * 3.14159265358979323846 / 4096.0) * (float)r;
    float sn, cn; sincosf(th, &sn, &cn);
    float v = (c < 16) ? cn : -sn;
    etab[k] = packsplit(v);
  }
  for (int k = idx; k < NL * HID * HID; k += stride) {  // natural [l][o][c]
    float w = skip_w[k];
    unsigned short hi = f2bf(w);
    skh[k] = hi; skl[k] = f2bf(w - bf2f(hi));
  }
  for (int k = idx; k < HID * LIFT; k += stride) {      // natural [o][c2]
    float w = lift_w2[k];
    unsigned short hi = f2bf(w);
    w2hi[k] = hi; w2lo[k] = f2bf(w - bf2f(hi));
  }
  for (int k = idx; k < LIFT * HID; k += stride) {      // natural [c2][c]
    float w = proj_w1[k];
    unsigned short hi = f2bf(w);
    p1hi[k] = hi; p1lo[k] = f2bf(w - bf2f(hi));
  }
  for (int k = idx; k < LIFT; k += stride) {            // packed lift stage-1
    w1b[k] = make_float4(lift_w1[2 * k], lift_w1[2 * k + 1], lift_b1[k], 0.f);
  }
  for (int k = idx; k < 12288; k += stride)             // zero part
    ws[OFF_PART + k] = 0.f;
}

// ---------------------------------------------------------------- lift ----
// grid (S/128, B), block 128 (2 waves), (128,3) — R13 exact (best measured;
// the (128,4) bound spilled catastrophically: R14). Per-wave work: 64
// s-cols, nt=4, acc[4][4], padded float4 W1B loads.
__global__ __launch_bounds__(128, 3) void k_lift(
    const float* __restrict__ x, const float4* __restrict__ W1B,
    const float* __restrict__ b2,
    const unsigned short* __restrict__ Whi,
    const unsigned short* __restrict__ Wlo,
    unsigned* __restrict__ Hp) {
  int tid = threadIdx.x;
  int b = blockIdx.y, s0 = blockIdx.x * 128;
  int lane = tid & 63, wv = tid >> 6, quad = lane >> 4, n16 = lane & 15;
  int sw = s0 + wv * 64;
  int cq = quad * 8;    // lane's j-base inside each 32-row K-chunk
  float2 xv[4];
  #pragma unroll
  for (int nt = 0; nt < 4; ++nt)
    xv[nt] = ((const float2*)x)[b * S_ + sw + nt * 16 + n16];
  f32x4 acc[4][4];
  #pragma unroll
  for (int mt = 0; mt < 4; ++mt)
    #pragma unroll
    for (int nt = 0; nt < 4; ++nt) acc[mt][nt] = (f32x4){0.f, 0.f, 0.f, 0.f};

  #pragma unroll 1
  for (int k = 0; k < 8; ++k) {
    short8 ah[4], al[4];
    #pragma unroll
    for (int mt = 0; mt < 4; ++mt) {
      int aoff = (mt * 16 + n16) * 256 + k * 32 + cq;
      ah[mt] = *(const short8*)(Whi + aoff);
      al[mt] = *(const short8*)(Wlo + aoff);
    }
    float4 w[8];
    #pragma unroll
    for (int j = 0; j < 8; ++j) w[j] = W1B[k * 32 + cq + j];
    #pragma unroll
    for (int nt = 0; nt < 4; ++nt) {
      float t[8];
      #pragma unroll
      for (int j = 0; j < 8; ++j)
        t[j] = gelu_f(w[j].x * xv[nt].x + w[j].y * xv[nt].y + w[j].z);
      short8 bh, bl;
      unsigned* bhw = (unsigned*)&bh;
      unsigned* blw = (unsigned*)&bl;
      #pragma unroll
      for (int p = 0; p < 4; ++p)
        split2pk(t[2*p], t[2*p+1], bhw[p], blw[p]);
      #pragma unroll
      for (int mt = 0; mt < 4; ++mt) {
        acc[mt][nt] = MFMA16(ah[mt], bh, acc[mt][nt], 0, 0, 0);
        acc[mt][nt] = MFMA16(ah[mt], bl, acc[mt][nt], 0, 0, 0);
        acc[mt][nt] = MFMA16(al[mt], bh, acc[mt][nt], 0, 0, 0);
      }
    }
  }
  #pragma unroll
  for (int mt = 0; mt < 4; ++mt) {
    int o0 = mt * 16 + quad * 4;
    float4 bb = *(const float4*)&b2[o0];
    #pragma unroll
    for (int nt = 0; nt < 4; ++nt) {
      int sc = sw + nt * 16 + n16;
      unsigned* hp = Hp + ((size_t)b * HID + o0) * S_ + sc;
      unsigned u0, u1, u2, u3;
      packsplit2(acc[mt][nt][0] + bb.x, acc[mt][nt][1] + bb.y, u0, u1);
      packsplit2(acc[mt][nt][2] + bb.z, acc[mt][nt][3] + bb.w, u2, u3);
      hp[0]            = u0;
      hp[(size_t)S_]   = u1;
      hp[(size_t)2*S_] = u2;
      hp[(size_t)3*S_] = u3;
    }
  }
}

// --------------------------------------------------------- forward DFT ----
// R16: grid (4 msplit, B), block 1024 (16 waves), (1024,4) -> 256 blocks =
// 1 block/CU = 4 waves/SIMD (same occupancy as old (256,4) ksplit form).
// Wave wv covers K-chunk [wv*256, +256) — per-wave inner work byte-
// identical to the old g=ks*4+wv version. Each (i0,b) entry now has a
// SINGLE writer: 16-partial LDS reduce + plain store. Eliminates the
// per-layer hipMemsetAsync AND 512 fp32 atomics/block (2M/layer). The
// 16-term deterministic sum replaces a nondeterministic atomic-order sum
// (same perturbation class, already tolerated at 2.3e-10).
__global__ __launch_bounds__(1024, 4) void k_fft_fwd(
    const unsigned* __restrict__ Hp, const unsigned* __restrict__ Etab,
    float* __restrict__ xf) {
  __shared__ float red[16 * 512];
  int tid = threadIdx.x;
  int i0 = blockIdx.x * 16, b = blockIdx.y;
  int lane = tid & 63, wv = tid >> 6, quad = lane >> 4, n16 = lane & 15;
  const unsigned* hb = Hp + ((size_t)b * HID + i0 + n16) * S_;
  int g = wv;                        // K-chunk 0..15
  f32x4 acc0 = (f32x4){0.f,0.f,0.f,0.f}, acc1 = (f32x4){0.f,0.f,0.f,0.f};
  #pragma unroll 1
  for (int kt = 0; kt < 8; ++kt) {
    int sb = g * 256 + kt * 32 + quad * 8;
    uint8v av = *(const uint8v*)(hb + sb);
    short8 ah, al;
    unpk8v(av, ah, al);
    unsigned q0[8], q1[8];
    #pragma unroll
    for (int j = 0; j < 8; ++j) {
      q0[j] = Etab[(sb + j) * 32 + n16];
      q1[j] = Etab[(sb + j) * 32 + 16 + n16];
    }
    short8 bh0, bl0, bh1, bl1;
    unpk8(q0, bh0, bl0);
    unpk8(q1, bh1, bl1);
    acc0 = MFMA16(ah, bh0, acc0, 0, 0, 0);
    acc0 = MFMA16(ah, bl0, acc0, 0, 0, 0);
    acc0 = MFMA16(al, bh0, acc0, 0, 0, 0);
    acc1 = MFMA16(ah, bh1, acc1, 0, 0, 0);
    acc1 = MFMA16(ah, bl1, acc1, 0, 0, 0);
    acc1 = MFMA16(al, bh1, acc1, 0, 0, 0);
  }
  // D: row = quad*4+r (i_local), col = n16 (+16 for acc1)
  #pragma unroll
  for (int r = 0; r < 4; ++r) {
    red[wv * 512 + (quad * 4 + r) * 32 + n16]      = acc0[r];
    red[wv * 512 + (quad * 4 + r) * 32 + 16 + n16] = acc1[r];
  }
  __syncthreads();
  if (tid < 512) {
    int il = tid >> 5, c = tid & 31;
    float v = 0.f;
    #pragma unroll
    for (int w = 0; w < 16; ++w) v += red[w * 512 + tid];
    xf[(size_t)b * 2048 + (i0 + il) * 32 + c] = v;   // single writer
  }
}

// ----------------------------------------------------------- mode mix ----
// grid (B), block 256, single block per b (in-place safe: ALL of xf[b] is
// staged to LDS before any yk write). Thread owns (o = tid>>2, m = mq..mq+3)
// -> weight reads are 2 float4 vloads per i2; LDS reads broadcast. Per-
// output i2 chain unchanged -> bit-identical. (R12 proven: -12us)
__global__ __launch_bounds__(256) void k_mix(
    const float* __restrict__ wr_, const float* __restrict__ wi_,
    float* __restrict__ xfy) {
  int tid = threadIdx.x;
  int b = blockIdx.x;
  __shared__ float xr[HID * MODES], xi[HID * MODES];
  const float* xfb = xfy + (size_t)b * 2048;
  for (int u = tid; u < HID * MODES; u += 256) {
    int i = u >> 4, m = u & 15;
    xr[u] = xfb[i * 32 + m];
    xi[u] = xfb[i * 32 + 16 + m];
  }
  __syncthreads();
  const float invS = 1.0f / (float)S_;
  unsigned* yk = (unsigned*)xfy + (size_t)b * 2048;
  int o = tid >> 2, mq = (tid & 3) * 4;
  float yr[4] = {0.f, 0.f, 0.f, 0.f};
  float yj[4] = {0.f, 0.f, 0.f, 0.f};
  for (int i2 = 0; i2 < HID; ++i2) {
    float4 w4 = *(const float4*)&wr_[((size_t)i2 * HID + o) * MODES + mq];
    float4 v4 = *(const float4*)&wi_[((size_t)i2 * HID + o) * MODES + mq];
    float4 x4 = *(const float4*)&xr[i2 * MODES + mq];
    float4 y4 = *(const float4*)&xi[i2 * MODES + mq];
    yr[0] += x4.x * w4.x - y4.x * v4.x;  yj[0] += x4.x * v4.x + y4.x * w4.x;
    yr[1] += x4.y * w4.y - y4.y * v4.y;  yj[1] += x4.y * v4.y + y4.y * w4.y;
    yr[2] += x4.z * w4.z - y4.z * v4.z;  yj[2] += x4.z * v4.z + y4.z * w4.z;
    yr[3] += x4.w * w4.w - y4.w * v4.w;  yj[3] += x4.w * v4.w + y4.w * w4.w;
  }
  #pragma unroll
  for (int mm = 0; mm < 4; ++mm) {
    int m = mq + mm;
    float fac = (m == 0) ? invS : 2.f * invS;
    unsigned ur, ui;
    packsplit2(yr[mm] * fac, yj[mm] * fac, ur, ui);
    yk[o * 32 + m]      = ur;
    yk[o * 32 + 16 + m] = ui;
  }
}

// --------------------------------------------- irfft + skip + (gelu) ----
// grid (S/128, B), block 128 (2 waves), (128,3) — R13-proven. Per-wave
// work identical; v_perm unpacks + packsplit2 epilogue; scalar bias+gelu
// (bit-stable). In-place safe: wave-private columns.
template <bool ACT>
__global__ __launch_bounds__(128, 3) void k_spec_skip(
    const unsigned short* __restrict__ Shi,
    const unsigned short* __restrict__ Slo,
    const float* __restrict__ skb,
    const unsigned* __restrict__ Yk,
    const unsigned* __restrict__ Etab,
    unsigned* __restrict__ Hp) {
  int tid = threadIdx.x;
  int s0 = blockIdx.x * 128, b = blockIdx.y;
  int lane = tid & 63, wv = tid >> 6, quad = lane >> 4, n16 = lane & 15;
  int sw = s0 + wv * 64;
  f32x4 acc[4][4];
  #pragma unroll
  for (int mt = 0; mt < 4; ++mt)
    #pragma unroll
    for (int nt = 0; nt < 4; ++nt) acc[mt][nt] = (f32x4){0.f,0.f,0.f,0.f};
  // ---- irfft phase: yk A-frags live only in this scope ----
  {
    short8 yh[4], yl[4];
    #pragma unroll
    for (int mt = 0; mt < 4; ++mt) {
      uint8v yv = *(const uint8v*)(Yk + (size_t)b * 2048 + (mt * 16 + n16) * 32 + quad * 8);
      unpk8v(yv, yh[mt], yl[mt]);
    }
    #pragma unroll
    for (int nt = 0; nt < 4; ++nt) {
      int sc = sw + nt * 16 + n16;
      uint8v tv = *(const uint8v*)(Etab + (size_t)sc * 32 + quad * 8);
      short8 th, tl;
      unpk8v(tv, th, tl);
      #pragma unroll
      for (int mt = 0; mt < 4; ++mt) {
        acc[mt][nt] = MFMA16(yh[mt], th, acc[mt][nt], 0, 0, 0);
        acc[mt][nt] = MFMA16(yh[mt], tl, acc[mt][nt], 0, 0, 0);
        acc[mt][nt] = MFMA16(yl[mt], th, acc[mt][nt], 0, 0, 0);
      }
    }
  }
  // ---- skip GEMM: K=64 (2 ksteps); A-frags loaded per-kk ----
  const unsigned* hb = Hp + (size_t)b * HID * S_;
  #pragma unroll
  for (int kk = 0; kk < 2; ++kk) {
    short8 skh[4], skl[4];
    #pragma unroll
    for (int mt = 0; mt < 4; ++mt) {
      int off = (mt * 16 + n16) * 64 + kk * 32 + quad * 8;
      skh[mt] = *(const short8*)(Shi + off);
      skl[mt] = *(const short8*)(Slo + off);
    }
    #pragma unroll
    for (int nt = 0; nt < 4; ++nt) {
      int sc = sw + nt * 16 + n16;
      unsigned pk[8];
      #pragma unroll
      for (int j = 0; j < 8; ++j)
        pk[j] = hb[(size_t)(kk * 32 + quad * 8 + j) * S_ + sc];
      short8 bh, bl;
      unpk8(pk, bh, bl);
      #pragma unroll
      for (int mt = 0; mt < 4; ++mt) {
        acc[mt][nt] = MFMA16(skh[mt], bh, acc[mt][nt], 0, 0, 0);
        acc[mt][nt] = MFMA16(skh[mt], bl, acc[mt][nt], 0, 0, 0);
        acc[mt][nt] = MFMA16(skl[mt], bh, acc[mt][nt], 0, 0, 0);
      }
    }
  }
  // epilogue: bias + (gelu) + pack + store
  #pragma unroll
  for (int mt = 0; mt < 4; ++mt) {
    int o0 = mt * 16 + quad * 4;
    float4 bb = *(const float4*)&skb[o0];
    #pragma unroll
    for (int nt = 0; nt < 4; ++nt) {
      int sc = sw + nt * 16 + n16;
      float v0 = acc[mt][nt][0] + bb.x;
      float v1 = acc[mt][nt][1] + bb.y;
      float v2 = acc[mt][nt][2] + bb.z;
      float v3 = acc[mt][nt][3] + bb.w;
      if (ACT) { v0 = gelu_f(v0); v1 = gelu_f(v1); v2 = gelu_f(v2); v3 = gelu_f(v3); }
      unsigned u0, u1, u2, u3;
      packsplit2(v0, v1, u0, u1);
      packsplit2(v2, v3, u2, u3);
      unsigned* hp = Hp + ((size_t)b * HID + o0) * S_ + sc;
      hp[0]            = u0;
      hp[(size_t)S_]   = u1;
      hp[(size_t)2*S_] = u2;
      hp[(size_t)3*S_] = u3;
    }
  }
}

// ------------------------------------------------- projection + mean ----
// grid (S/64, B), block 512 (8 waves), (512,6) — R13 form. Tile staged
// ONCE, conflict-free frag-ready pair-dword layout; single-writer part
// stores; scalar epilogue bit-stable.
__global__ __launch_bounds__(512, 6) void k_proj(
    const unsigned short* __restrict__ Phi,
    const unsigned short* __restrict__ Plo,
    const float* __restrict__ pb1, const float* __restrict__ pw2,
    const unsigned* __restrict__ Hp, float* __restrict__ part) {
  __shared__ unsigned BpH[64 * 34];
  __shared__ unsigned BpL[64 * 34];
  __shared__ float red[24];
  int tid = threadIdx.x;
  int s0 = blockIdx.x * 64, b = blockIdx.y;
  int lane = tid & 63, wv = tid >> 6, quad = lane >> 4, n16 = lane & 15;
  {
    int cg = wv & 3, u0b = (wv >> 2) * 4;
    const unsigned* hpb = Hp + ((size_t)b * HID + cg * 16) * S_ + s0 + lane;
    #pragma unroll
    for (int uu = 0; uu < 4; ++uu) {
      int up = u0b + uu;
      unsigned u0 = hpb[(size_t)(2 * up) * S_];
      unsigned u1 = hpb[(size_t)(2 * up + 1) * S_];
      BpH[lane * 34 + cg * 8 + up] = __builtin_amdgcn_perm(u1, u0, 0x05040100u);
      BpL[lane * 34 + cg * 8 + up] = __builtin_amdgcn_perm(u1, u0, 0x07060302u);
    }
  }
  __syncthreads();
  int m0 = wv * 32;                      // wave owns c2 rows [m0, m0+32)
  f32x4 acc[2][4];
  #pragma unroll
  for (int mt = 0; mt < 2; ++mt)
    #pragma unroll
    for (int nt = 0; nt < 4; ++nt) acc[mt][nt] = (f32x4){0.f,0.f,0.f,0.f};
  #pragma unroll
  for (int kk = 0; kk < 2; ++kk) {
    int kb = kk * 16 + quad * 4;   // dword col base = 8 channels
    short8 ah[2], al[2];
    #pragma unroll
    for (int mt = 0; mt < 2; ++mt) {
      int aoff = (m0 + mt * 16 + n16) * 64 + kk * 32 + quad * 8;
      ah[mt] = *(const short8*)(Phi + aoff);
      al[mt] = *(const short8*)(Plo + aoff);
    }
    #pragma unroll
    for (int nt = 0; nt < 4; ++nt) {
      int sc = nt * 16 + n16;
      union { unsigned u[4]; short8 s; } Bh, Bl;
      *(uint2*)&Bh.u[0] = *(const uint2*)&BpH[sc * 34 + kb];
      *(uint2*)&Bh.u[2] = *(const uint2*)&BpH[sc * 34 + kb + 2];
      *(uint2*)&Bl.u[0] = *(const uint2*)&BpL[sc * 34 + kb];
      *(uint2*)&Bl.u[2] = *(const uint2*)&BpL[sc * 34 + kb + 2];
      #pragma unroll
      for (int mt = 0; mt < 2; ++mt) {
        acc[mt][nt] = MFMA16(ah[mt], Bh.s, acc[mt][nt], 0, 0, 0);
        acc[mt][nt] = MFMA16(ah[mt], Bl.s, acc[mt][nt], 0, 0, 0);
        acc[mt][nt] = MFMA16(al[mt], Bh.s, acc[mt][nt], 0, 0, 0);
      }
    }
  }
  // epilogue (scalar, bit-stable): gelu + pw2 dot + wave/block reduce
  float o0 = 0.f, o1 = 0.f, o2 = 0.f;
  #pragma unroll
  for (int mt = 0; mt < 2; ++mt) {
    int c2b = m0 + mt * 16 + quad * 4;
    float4 bb = *(const float4*)&pb1[c2b];
    float4 p0 = *(const float4*)&pw2[c2b];
    float4 p1 = *(const float4*)&pw2[256 + c2b];
    float4 p2 = *(const float4*)&pw2[512 + c2b];
    #pragma unroll
    for (int nt = 0; nt < 4; ++nt) {
      f32x4 a = acc[mt][nt];
      float t0 = gelu_f(a[0] + bb.x);
      float t1 = gelu_f(a[1] + bb.y);
      float t2 = gelu_f(a[2] + bb.z);
      float t3 = gelu_f(a[3] + bb.w);
      o0 += p0.x * t0 + p0.y * t1 + p0.z * t2 + p0.w * t3;
      o1 += p1.x * t0 + p1.y * t1 + p1.z * t2 + p1.w * t3;
      o2 += p2.x * t0 + p2.y * t1 + p2.z * t2 + p2.w * t3;
    }
  }
  #pragma unroll
  for (int off = 32; off > 0; off >>= 1) {
    o0 += __shfl_xor(o0, off, 64);
    o1 += __shfl_xor(o1, off, 64);
    o2 += __shfl_xor(o2, off, 64);
  }
  if (lane == 0) { red[wv*3+0] = o0; red[wv*3+1] = o1; red[wv*3+2] = o2; }
  __syncthreads();
  if (tid < 3) {
    float sum = 0.f;
    #pragma unroll
    for (int k = 0; k < 8; ++k) sum += red[k * 3 + tid];
    part[(b * 64 + blockIdx.x) * 3 + tid] = sum;   // single writer
  }
}

__global__ void k_final(const float* __restrict__ part,
                        const float* __restrict__ pb2,
                        float* __restrict__ out) {
  int t = threadIdx.x;
  if (t < B_ * 3) {
    int b = t / 3, j = t % 3;
    float s = 0.f;
    for (int k = 0; k < 64; ++k) s += part[(b * 64 + k) * 3 + j];
    out[t] = s * (1.0f / (float)S_) + pb2[j];
  }
}

// ------------------------------------------------------------- launch ----
extern "C" void kernel_launch(void* const* d_in, const int* in_sizes, int n_in,
                              void* d_out, int out_size, void* d_ws, size_t ws_size,
                              hipStream_t stream) {
  const float* x   = (const float*)d_in[0];
  const float* lw1 = (const float*)d_in[1];
  const float* lb1 = (const float*)d_in[2];
  const float* lw2 = (const float*)d_in[3];
  const float* lb2 = (const float*)d_in[4];
  const float* swr = (const float*)d_in[5];
  const float* swi = (const float*)d_in[6];
  const float* skw = (const float*)d_in[7];
  const float* skb = (const float*)d_in[8];
  const float* pw1 = (const float*)d_in[9];
  const float* pb1 = (const float*)d_in[10];
  const float* pw2 = (const float*)d_in[11];
  const float* pb2 = (const float*)d_in[12];
  float* ws = (float*)d_ws;
  unsigned* Hp  = (unsigned*)(ws + OFF_H);
  unsigned* ETB = (unsigned*)(ws + OFF_ETB);
  float*    XFY = ws + OFF_XFY;

  k_init<<<256, 256, 0, stream>>>(lw2, skw, pw1, lw1, lb1, ws);
  k_lift<<<dim3(S_ / 128, B_), 128, 0, stream>>>(
      x, (const float4*)(ws + OFF_W1B), lb2,
      (const unsigned short*)(ws + OFF_W2HI),
      (const unsigned short*)(ws + OFF_W2LO), Hp);
  for (int l = 0; l < NL; ++l) {
    // no memset: k_fft_fwd is now single-writer per xf entry
    k_fft_fwd<<<dim3(4, B_), 1024, 0, stream>>>(Hp, ETB, XFY);
    k_mix<<<B_, 256, 0, stream>>>(swr + l * HID * HID * MODES,
                                  swi + l * HID * HID * MODES, XFY);
    if (l < NL - 1)
      k_spec_skip<true><<<dim3(S_ / 128, B_), 128, 0, stream>>>(
          (const unsigned short*)(ws + OFF_SKH) + l * HID * HID,
          (const unsigned short*)(ws + OFF_SKL) + l * HID * HID,
          skb + l * HID, (const unsigned*)XFY, ETB, Hp);
    else
      k_spec_skip<false><<<dim3(S_ / 128, B_), 128, 0, stream>>>(
          (const unsigned short*)(ws + OFF_SKH) + l * HID * HID,
          (const unsigned short*)(ws + OFF_SKL) + l * HID * HID,
          skb + l * HID, (const unsigned*)XFY, ETB, Hp);
  }
  k_proj<<<dim3(S_ / 64, B_), 512, 0, stream>>>(
      (const unsigned short*)(ws + OFF_P1HI),
      (const unsigned short*)(ws + OFF_P1LO),
      pb1, pw2, Hp, ws + OFF_PART);
  k_final<<<1, 256, 0, stream>>>(ws + OFF_PART, pb2, (float*)d_out);
}